// Round 18
// baseline (429.711 us; speedup 1.0000x reference)
//
#include <hip/hip_runtime.h>
#include <math.h>

#define N_TOK 131072
#define D 256
#define K_CODES 1024

typedef short bf16x8 __attribute__((ext_vector_type(8)));
typedef float f32x4 __attribute__((ext_vector_type(4)));

__device__ __forceinline__ unsigned short f2bf(float f) {
  unsigned x = __float_as_uint(f);
  unsigned r = x + 0x7fffu + ((x >> 16) & 1u);
  return (unsigned short)(r >> 16);
}

// ---------------------------------------------------------------- kernel 1
// fp64 code norms -> inv_nc64 (exact anchor, VALIDATED r8).
// cbb written FRAGMENT-MAJOR (VALIDATED r17): (c,d) -> frag[((c>>4)*8+(d>>5))
//   *64 + ((d>>3)&3)*16 + (c&15)][d&7]
__global__ __launch_bounds__(256) void norm_cb_kernel(
    const float* __restrict__ cb, double* __restrict__ inv_nc64,
    unsigned short* __restrict__ cbbf) {
  const int c = blockIdx.x;
  const int d = threadIdx.x;
  const float v = cb[(size_t)c * D + d];
  double ssd = (double)v * (double)v;
#pragma unroll
  for (int o = 32; o; o >>= 1) ssd += __shfl_down(ssd, o, 64);
  __shared__ double red[4];
  if ((d & 63) == 0) red[d >> 6] = ssd;
  __syncthreads();
  const double tot = red[0] + red[1] + red[2] + red[3];
  const double inv = 1.0 / fmax(sqrt(tot), 1e-12);
  if (d == 0) inv_nc64[c] = inv;
  const int ctile = c >> 4, tk = c & 15;
  const int s = d >> 5, kg = (d >> 3) & 3, e = d & 7;
  cbbf[(((size_t)(ctile * 8 + s) * 64) + (kg * 16 + tk)) * 8 + e] =
      f2bf((float)((double)v * inv));
}

// ---------------------------------------------------------------- kernel 2
// bf16 MFMA sims, barrier-free K loop + fragment-major cf stream (VALIDATED
// r17). r18: 64 tokens/block (2x arithmetic intensity), inv_zn fused here.
__global__ __launch_bounds__(512, 1) void vq_mfma_kernel(
    const float* __restrict__ z, const char* __restrict__ cbbf,
    float* __restrict__ out_codes, float* __restrict__ inv_zn,
    unsigned long long* __restrict__ cand2) {
  __shared__ __align__(16) char S[32768];  // z tile bf16, swizzled 16B units
  __shared__ float norms[64];
  __shared__ int cand[64 * 8 * 3];
  __shared__ int clist[64 * 12];
  __shared__ float thrs[64];
  __shared__ int ccnt[64];

  const int tid = threadIdx.x;
  const int wv = tid >> 6;
  const int lane = tid & 63;
  const int t0b = blockIdx.x * 64;

  // ---- prologue: stage z (fp32->bf16, swizzled) + norms + inv_zn
  // (validated r3-r12 64-token staging: 8 threads per token)
  {
    const int tok = tid >> 3, sub = tid & 7;
    const float* zrow = z + (size_t)(t0b + tok) * D;
    float ss = 0.f;
#pragma unroll
    for (int i = 0; i < 4; ++i) {
      const int ku = sub + 8 * i;
      const float4 a = *(const float4*)(zrow + ku * 8);
      const float4 b = *(const float4*)(zrow + ku * 8 + 4);
      ss += a.x * a.x + a.y * a.y + a.z * a.z + a.w * a.w;
      ss += b.x * b.x + b.y * b.y + b.z * b.z + b.w * b.w;
      union { unsigned short h[8]; int4 v; } u;
      u.h[0] = f2bf(a.x); u.h[1] = f2bf(a.y); u.h[2] = f2bf(a.z); u.h[3] = f2bf(a.w);
      u.h[4] = f2bf(b.x); u.h[5] = f2bf(b.y); u.h[6] = f2bf(b.z); u.h[7] = f2bf(b.w);
      const int phys = (tok << 5) + (ku ^ (tok & 15));
      *(int4*)(S + ((size_t)phys << 4)) = u.v;
    }
    ss += __shfl_xor(ss, 1, 64);
    ss += __shfl_xor(ss, 2, 64);
    ss += __shfl_xor(ss, 4, 64);
    if (sub == 0) {
      const float nr = sqrtf(ss);
      norms[tok] = nr;
      inv_zn[t0b + tok] = 1.0f / fmaxf(nr, 1e-12f);
    }
  }
  __syncthreads();

  const int tk = lane & 15;
  const int kg = lane >> 4;

  f32x4 acc[4][8];
#pragma unroll
  for (int t = 0; t < 4; ++t)
#pragma unroll
    for (int c = 0; c < 8; ++c) acc[t][c] = (f32x4){0.f, 0.f, 0.f, 0.f};

  // wave's fragment stream base: ctiles wv*8..wv*8+7, 8KB per ctile
  const char* cfb = cbbf + (size_t)wv * 65536 + (size_t)lane * 16;

  // ---- K loop: 8 k-slices, fully unrolled, NO barriers
#pragma unroll
  for (int s = 0; s < 8; ++s) {
    bf16x8 zf[4];
#pragma unroll
    for (int tt = 0; tt < 4; ++tt) {
      const int tok = tt * 16 + tk;
      const int ku = (s << 2) + kg;
      zf[tt] = *(const bf16x8*)(S + (((tok << 5) + (ku ^ (tok & 15))) << 4));
    }
#pragma unroll
    for (int ct = 0; ct < 8; ++ct) {
      const bf16x8 cf = *(const bf16x8*)(cfb + ct * 8192 + s * 1024);
      acc[0][ct] = __builtin_amdgcn_mfma_f32_16x16x32_bf16(cf, zf[0], acc[0][ct], 0, 0, 0);
      acc[1][ct] = __builtin_amdgcn_mfma_f32_16x16x32_bf16(cf, zf[1], acc[1][ct], 0, 0, 0);
      acc[2][ct] = __builtin_amdgcn_mfma_f32_16x16x32_bf16(cf, zf[2], acc[2][ct], 0, 0, 0);
      acc[3][ct] = __builtin_amdgcn_mfma_f32_16x16x32_bf16(cf, zf[3], acc[3][ct], 0, 0, 0);
    }
  }

  // ---- per-wave top-2 (index for top-1) per token -> cand area
  // acc[tt][ct]: code = (wv<<7) + (ct<<4) + (kg<<2) + r   (VALIDATED r10)
#pragma unroll
  for (int tt = 0; tt < 4; ++tt) {
    float t1 = -3.0e38f, t2 = -3.0e38f;
    int i1 = 0;
#pragma unroll
    for (int ct = 0; ct < 8; ++ct)
#pragma unroll
      for (int r = 0; r < 4; ++r) {
        const float v = acc[tt][ct][r];
        const int k = (wv << 7) + (ct << 4) + (kg << 2) + r;
        if (v > t1) { t2 = t1; t1 = v; i1 = k; }
        else if (v > t2) t2 = v;
      }
#pragma unroll
    for (int off = 16; off <= 32; off <<= 1) {
      const float o1 = __shfl_xor(t1, off, 64);
      const int oi1 = __shfl_xor(i1, off, 64);
      const float o2 = __shfl_xor(t2, off, 64);
      const bool take = (o1 > t1) || (o1 == t1 && oi1 < i1);
      const float lo = take ? t1 : o1;
      t1 = take ? o1 : t1;
      i1 = take ? oi1 : i1;
      t2 = fmaxf(fmaxf(t2, o2), lo);
    }
    if (lane < 16) {
      int* p = cand + ((tt * 16 + lane) * 8 + wv) * 3;
      p[0] = __float_as_int(t1);
      p[1] = i1;
      p[2] = __float_as_int(t2);
    }
  }
  __syncthreads();

  // ---- resolver pass 1: thr + certified decision
  if (tid < 64) {
    const float nrm = norms[tid];
    const float margin = 0.016f * nrm + 1.5e-3f;  // 2*(2^-8+2^-8)*||z|| + slack
    const int* base = cand + tid * 24;
    float v1 = -3.0e38f, v2 = -3.0e38f;
    int j1 = 0x7fffffff;
#pragma unroll
    for (int w = 0; w < 8; ++w) {
      const float a1 = __int_as_float(base[w * 3]);
      const int ai = base[w * 3 + 1];
      const float a2 = __int_as_float(base[w * 3 + 2]);
      const bool take = (a1 > v1) || (a1 == v1 && ai < j1);
      const float lo = take ? v1 : a1;
      v1 = take ? a1 : v1;
      j1 = take ? ai : j1;
      v2 = fmaxf(fmaxf(v2, a2), lo);
    }
    const float thr = v1 - margin;
    thrs[tid] = (v2 < thr) ? 3.0e38f : thr;
    ccnt[tid] = 0;
    out_codes[t0b + tid] = (float)j1;  // final if certified, else provisional
  }
  __syncthreads();

  // ---- collect pass: append every code with S_bf >= thr (flagged tokens)
#pragma unroll
  for (int tt = 0; tt < 4; ++tt) {
    const int tok = tt * 16 + tk;
    const float thr_t = thrs[tok];
#pragma unroll
    for (int ct = 0; ct < 8; ++ct)
#pragma unroll
      for (int r = 0; r < 4; ++r) {
        if (acc[tt][ct][r] >= thr_t) {
          const int pos = atomicAdd(&ccnt[tok], 1);
          if (pos < 12)
            clist[tok * 12 + pos] = (wv << 7) + (ct << 4) + (kg << 2) + r;
        }
      }
  }
  __syncthreads();

  // ---- resolver pass 2: dense record (no caps, no fallback)
  if (tid < 64) {
    const int cnt = ccnt[tid];
    unsigned long long w0 = 0, w1 = 0;
    if (cnt > 0) {
      const int cc = cnt > 15 ? 15 : cnt;        // >12 -> full-scan flag
      w0 = (unsigned long long)cc << 60;
      const int nst = cnt > 12 ? 12 : cnt;
      for (int j = 0; j < nst && j < 6; ++j)
        w0 |= ((unsigned long long)(clist[tid * 12 + j] & 1023)) << (10 * j);
      for (int j = 6; j < nst; ++j)
        w1 |= ((unsigned long long)(clist[tid * 12 + j] & 1023)) << (10 * (j - 6));
    }
    cand2[2 * (t0b + tid)] = w0;
    cand2[2 * (t0b + tid) + 1] = w1;
  }
}

// ---------------------------------------------------------------- kernel 3
// exact recheck (r8-VALIDATED math) for cnt<=12; cnt>12 -> capless ovf list
__global__ __launch_bounds__(256) void recheck_kernel(
    const float* __restrict__ z, const float* __restrict__ cb,
    const double* __restrict__ inv_nc64,
    const unsigned long long* __restrict__ cand2,
    float* __restrict__ out_codes, int* __restrict__ ovf_list,
    int* __restrict__ ovf_cnt) {
  const int lane = threadIdx.x & 63;
  const int wid = (blockIdx.x * blockDim.x + threadIdx.x) >> 6;
  const int nw = (gridDim.x * blockDim.x) >> 6;
  for (int t = wid; t < N_TOK; t += nw) {
    const unsigned long long w0 = cand2[2 * t];
    if (w0 == 0ull) continue;
    const int cnt = (int)(w0 >> 60);
    if (cnt > 12) {  // defer to block-parallel full scan (capless list)
      if (lane == 0) ovf_list[atomicAdd(ovf_cnt, 1)] = t;
      continue;
    }
    const float4 zr = *(const float4*)(z + (size_t)t * D + lane * 4);
    const double z0 = zr.x, z1 = zr.y, z2 = zr.z, z3 = zr.w;
    const unsigned long long w1 = cand2[2 * t + 1];
    double best = -1.0e300;
    int bi = 0x7fffffff;
    for (int j = 0; j < cnt; ++j) {
      const int c = (j < 6) ? (int)((w0 >> (10 * j)) & 1023)
                            : (int)((w1 >> (10 * (j - 6))) & 1023);
      const float4 cr = *(const float4*)(cb + (size_t)c * D + lane * 4);
      double p = z0 * (double)cr.x + z1 * (double)cr.y +
                 z2 * (double)cr.z + z3 * (double)cr.w;
#pragma unroll
      for (int o = 32; o; o >>= 1) p += __shfl_xor(p, o, 64);
      p *= inv_nc64[c];
      if (p > best || (p == best && c < bi)) { best = p; bi = c; }
    }
    if (lane == 0) out_codes[t] = (float)bi;
  }
}

// ---------------------------------------------------------------- kernel 4
// block-parallel full scan: one 256-thread block per ovf token, fp64
__global__ __launch_bounds__(256) void fullscan_kernel(
    const float* __restrict__ z, const float* __restrict__ cb,
    const double* __restrict__ inv_nc64, const int* __restrict__ ovf_list,
    const int* __restrict__ ovf_cnt, float* __restrict__ out_codes) {
  __shared__ float zs[256];
  __shared__ double bv[256];
  __shared__ int bis[256];
  const int n = *ovf_cnt;
  for (int i = blockIdx.x; i < n; i += gridDim.x) {
    const int t = ovf_list[i];
    zs[threadIdx.x] = z[(size_t)t * D + threadIdx.x];
    __syncthreads();
    double best = -1.0e300;
    int bidx = 0x7fffffff;
#pragma unroll
    for (int cc = 0; cc < 4; ++cc) {
      const int c = threadIdx.x + (cc << 8);
      const float4* crow = (const float4*)(cb + (size_t)c * D);
      double p = 0.0;
#pragma unroll 8
      for (int k4 = 0; k4 < 64; ++k4) {
        const float4 cv = crow[k4];
        p += (double)zs[4 * k4] * (double)cv.x +
             (double)zs[4 * k4 + 1] * (double)cv.y +
             (double)zs[4 * k4 + 2] * (double)cv.z +
             (double)zs[4 * k4 + 3] * (double)cv.w;
      }
      p *= inv_nc64[c];
      if (p > best || (p == best && c < bidx)) { best = p; bidx = c; }
    }
    bv[threadIdx.x] = best;
    bis[threadIdx.x] = bidx;
    __syncthreads();
    for (int s = 128; s; s >>= 1) {
      if (threadIdx.x < s) {
        const double ov = bv[threadIdx.x + s];
        const int oi = bis[threadIdx.x + s];
        if (ov > bv[threadIdx.x] ||
            (ov == bv[threadIdx.x] && oi < bis[threadIdx.x])) {
          bv[threadIdx.x] = ov;
          bis[threadIdx.x] = oi;
        }
      }
      __syncthreads();
    }
    if (threadIdx.x == 0) out_codes[t] = (float)bis[0];
    __syncthreads();
  }
}

// ---------------------------------------------------------------- kernel 5
// histogram of final codes
__global__ __launch_bounds__(256) void hist_kernel(
    const float* __restrict__ codesf, int* __restrict__ hist) {
  const int t = blockIdx.x * 256 + threadIdx.x;
  if (t < N_TOK) atomicAdd(&hist[(int)codesf[t]], 1);
}

// ---------------------------------------------------------------- kernel 6
// exclusive scan of hist[1024] -> offsets[1025]; cursor = offsets copy
__global__ __launch_bounds__(256) void scan_kernel(
    const int* __restrict__ hist, int* __restrict__ offsets,
    int* __restrict__ cursor) {
  __shared__ int part[256];
  const int tid = threadIdx.x;
  int v[4];
  int s = 0;
#pragma unroll
  for (int j = 0; j < 4; ++j) {
    v[j] = hist[tid * 4 + j];
    s += v[j];
  }
  part[tid] = s;
  __syncthreads();
  for (int off = 1; off < 256; off <<= 1) {
    int x = (tid >= off) ? part[tid - off] : 0;
    __syncthreads();
    part[tid] += x;
    __syncthreads();
  }
  int excl = part[tid] - s;
#pragma unroll
  for (int j = 0; j < 4; ++j) {
    offsets[tid * 4 + j] = excl;
    cursor[tid * 4 + j] = excl;
    excl += v[j];
  }
  if (tid == 255) offsets[1024] = excl;  // = N_TOK
}

// ---------------------------------------------------------------- kernel 7
// scatter token ids into per-code segments
__global__ __launch_bounds__(256) void scatter_kernel(
    const float* __restrict__ codesf, int* __restrict__ cursor,
    int* __restrict__ tlist) {
  const int t = blockIdx.x * 256 + threadIdx.x;
  if (t < N_TOK) {
    const int c = (int)codesf[t];
    const int pos = atomicAdd(&cursor[c], 1);
    tlist[pos] = t;
  }
}

// ---------------------------------------------------------------- kernel 8
// embed[c] = l2norm(0.97*ema_w[c] + 0.03 * sum z[t]*inv_zn[t])  (r13 form)
__global__ __launch_bounds__(256) void dw_build_kernel(
    const float* __restrict__ z, const int* __restrict__ tlist,
    const int* __restrict__ offsets, const float* __restrict__ inv_zn,
    const float* __restrict__ ema_w, float* __restrict__ embed) {
  const int c = blockIdx.x;
  const int d = threadIdx.x;
  const int i0 = offsets[c], i1 = offsets[c + 1];
  float sum = 0.f;
  for (int i = i0; i < i1; ++i) {
    const int t = tlist[i];
    sum += z[(size_t)t * D + d] * inv_zn[t];
  }
  const size_t idx = (size_t)c * D + d;
  const float w = 0.97f * ema_w[idx] + 0.03f * sum;
  float ss = w * w;
#pragma unroll
  for (int o = 32; o; o >>= 1) ss += __shfl_down(ss, o, 64);
  __shared__ float red[4];
  if ((d & 63) == 0) red[d >> 6] = ss;
  __syncthreads();
  const float tot = red[0] + red[1] + red[2] + red[3];
  embed[idx] = w / fmaxf(sqrtf(tot), 1e-12f);
}

// ---------------------------------------------------------------- kernel 9
__global__ __launch_bounds__(256) void gather_loss_kernel(
    const float* __restrict__ z, const float* __restrict__ embed,
    const float* __restrict__ codesf, float* __restrict__ out0,
    double* __restrict__ loss) {
  const size_t u0 = (size_t)blockIdx.x * 4096 + threadIdx.x;
  float part = 0.f;
#pragma unroll 4
  for (int i = 0; i < 16; ++i) {
    const size_t u = u0 + (size_t)i * 256;
    const size_t t = u >> 6;
    const int k4 = (int)(u & 63);
    const int code = (int)codesf[t];
    const float4 e = *(const float4*)(embed + (size_t)code * D + 4 * k4);
    const float4 ze = *(const float4*)(z + t * D + 4 * k4);
    *(float4*)(out0 + t * D + 4 * k4) = e;
    const float dx = ze.x - e.x, dy = ze.y - e.y;
    const float dz = ze.z - e.z, dw4 = ze.w - e.w;
    part += dx * dx + dy * dy + dz * dz + dw4 * dw4;
  }
#pragma unroll
  for (int o = 32; o; o >>= 1) part += __shfl_down(part, o, 64);
  __shared__ float red[4];
  if ((threadIdx.x & 63) == 0) red[threadIdx.x >> 6] = part;
  __syncthreads();
  if (threadIdx.x == 0)
    unsafeAtomicAdd(loss, (double)(red[0] + red[1] + red[2] + red[3]));
}

// ---------------------------------------------------------------- kernel 10
__global__ void finalize_kernel(const double* __restrict__ loss,
                                float* __restrict__ out2) {
  out2[0] = (float)(0.25 * loss[0] / 33554432.0);
}

// ---------------------------------------------------------------- launcher
extern "C" void kernel_launch(void* const* d_in, const int* in_sizes, int n_in,
                              void* d_out, int out_size, void* d_ws, size_t ws_size,
                              hipStream_t stream) {
  const float* z = (const float*)d_in[0];
  const float* cb = (const float*)d_in[1];
  const float* ema_w = (const float*)d_in[3];

  float* out0 = (float*)d_out;
  float* out1 = out0 + (size_t)N_TOK * D;
  float* out2 = out1 + N_TOK;

  // ws layout, max offset 3,154,048 (< r1-proven 3,670,144). Stream-ordered
  // aliasing identical to r16/r17 (validated). inv_zn now written by vq_mfma
  // (region [1.5M,2M) inside cand2 — BUT cand2 only occupies [1M,3M) as
  // 2x u64 per token = 2MB: cand2 spans [1M,3M). inv_zn aliases its middle.
  // FIX: inv_zn moved to [512K,1M)+... no — ovf_list lives there during
  // recheck. inv_zn gets its own slot AFTER cand2's live range? It's written
  // DURING vq_mfma while cand2 is being written. Place inv_zn in the tail
  // region [3,162,112) — outside all aliases (r1-proven ws >= 3.67MB).
  char* ws = (char*)d_ws;
  unsigned short* cbbf = (unsigned short*)ws;                       // [0, 512K)
  float* embed = (float*)ws;                                        // [0, 1M) alias
  int* ovf_list = (int*)(ws + 524288);                              // [512K, 1M)
  unsigned long long* cand2 = (unsigned long long*)(ws + 1048576);  // [1M, 3M)
  int* tlist = (int*)(ws + 1048576);                                // [1M, 1.5M) alias
  int* hist = (int*)(ws + 2097152);                                 // 4K alias
  int* offsets = (int*)(ws + 2101248);                              // 4K+4 alias
  int* cursor = (int*)(ws + 2105856);                               // 4K alias
  double* inv_nc64 = (double*)(ws + 3145728);                       // 8K
  double* loss = (double*)(ws + 3153920);                           // 8 B
  int* ovf_cnt = (int*)(ws + 3153984);                              // 4 B
  float* inv_zn = (float*)(ws + 3158016);                           // 512K tail

  hipMemsetAsync(ws + 3153920, 0, 128, stream);  // loss + ovf_cnt

  norm_cb_kernel<<<K_CODES, 256, 0, stream>>>(cb, inv_nc64, cbbf);
  vq_mfma_kernel<<<N_TOK / 64, 512, 0, stream>>>(
      z, (const char*)cbbf, out1, inv_zn, cand2);
  recheck_kernel<<<4096, 256, 0, stream>>>(z, cb, inv_nc64, cand2, out1,
                                           ovf_list, ovf_cnt);
  fullscan_kernel<<<2048, 256, 0, stream>>>(z, cb, inv_nc64, ovf_list,
                                            ovf_cnt, out1);
  hipMemsetAsync(hist, 0, 4096, stream);  // hist aliases dead cand2 region
  hist_kernel<<<N_TOK / 256, 256, 0, stream>>>(out1, hist);
  scan_kernel<<<1, 256, 0, stream>>>(hist, offsets, cursor);
  scatter_kernel<<<N_TOK / 256, 256, 0, stream>>>(out1, cursor, tlist);
  dw_build_kernel<<<K_CODES, 256, 0, stream>>>(z, tlist, offsets, inv_zn,
                                               ema_w, embed);
  gather_loss_kernel<<<2048, 256, 0, stream>>>(z, embed, out1, out0, loss);
  finalize_kernel<<<1, 1, 0, stream>>>(loss, out2);
}

// Round 19
// 394.428 us; speedup vs baseline: 1.0895x; 1.0895x over previous
//
#include <hip/hip_runtime.h>
#include <math.h>

#define N_TOK 131072
#define D 256
#define K_CODES 1024

typedef short bf16x8 __attribute__((ext_vector_type(8)));
typedef float f32x4 __attribute__((ext_vector_type(4)));

__device__ __forceinline__ unsigned short f2bf(float f) {
  unsigned x = __float_as_uint(f);
  unsigned r = x + 0x7fffu + ((x >> 16) & 1u);
  return (unsigned short)(r >> 16);
}

// ---------------------------------------------------------------- kernel 1
// fp64 code norms -> inv_nc64 (exact anchor, VALIDATED r8).
// cbb written FRAGMENT-MAJOR (VALIDATED r17): (c,d) -> frag[((c>>4)*8+(d>>5))
//   *64 + ((d>>3)&3)*16 + (c&15)][d&7]
__global__ __launch_bounds__(256) void norm_cb_kernel(
    const float* __restrict__ cb, double* __restrict__ inv_nc64,
    unsigned short* __restrict__ cbbf) {
  const int c = blockIdx.x;
  const int d = threadIdx.x;
  const float v = cb[(size_t)c * D + d];
  double ssd = (double)v * (double)v;
#pragma unroll
  for (int o = 32; o; o >>= 1) ssd += __shfl_down(ssd, o, 64);
  __shared__ double red[4];
  if ((d & 63) == 0) red[d >> 6] = ssd;
  __syncthreads();
  const double tot = red[0] + red[1] + red[2] + red[3];
  const double inv = 1.0 / fmax(sqrt(tot), 1e-12);
  if (d == 0) inv_nc64[c] = inv;
  const int ctile = c >> 4, tk = c & 15;
  const int s = d >> 5, kg = (d >> 3) & 3, e = d & 7;
  cbbf[(((size_t)(ctile * 8 + s) * 64) + (kg * 16 + tk)) * 8 + e] =
      f2bf((float)((double)v * inv));
}

// ---------------------------------------------------------------- kernel 2
// bf16 MFMA sims — EXACT r17-VALIDATED body (32 tok/block, barrier-free,
// fragment-major cf stream) + inv_zn write fused into the prologue.
__global__ __launch_bounds__(512, 2) void vq_mfma_kernel(
    const float* __restrict__ z, const char* __restrict__ cbbf,
    float* __restrict__ out_codes, float* __restrict__ inv_zn,
    unsigned long long* __restrict__ cand2) {
  __shared__ __align__(16) char S[16384];  // z tile bf16, swizzled 16B units
  __shared__ float norms[32];
  __shared__ int cand[32 * 8 * 3];
  __shared__ int clist[32 * 12];
  __shared__ float thrs[32];
  __shared__ int ccnt[32];

  const int tid = threadIdx.x;
  const int wv = tid >> 6;
  const int lane = tid & 63;
  const int t0b = blockIdx.x * 32;

  // ---- prologue: stage z (fp32->bf16, swizzled) + norms + inv_zn
  {
    const int tok = tid >> 4, sub = tid & 15;
    const float* zrow = z + (size_t)(t0b + tok) * D;
    float ss = 0.f;
#pragma unroll
    for (int i = 0; i < 2; ++i) {
      const int ku = sub + 16 * i;
      const float4 a = *(const float4*)(zrow + ku * 8);
      const float4 b = *(const float4*)(zrow + ku * 8 + 4);
      ss += a.x * a.x + a.y * a.y + a.z * a.z + a.w * a.w;
      ss += b.x * b.x + b.y * b.y + b.z * b.z + b.w * b.w;
      union { unsigned short h[8]; int4 v; } u;
      u.h[0] = f2bf(a.x); u.h[1] = f2bf(a.y); u.h[2] = f2bf(a.z); u.h[3] = f2bf(a.w);
      u.h[4] = f2bf(b.x); u.h[5] = f2bf(b.y); u.h[6] = f2bf(b.z); u.h[7] = f2bf(b.w);
      const int phys = (tok << 5) + (ku ^ (tok & 15));
      *(int4*)(S + ((size_t)phys << 4)) = u.v;
    }
    ss += __shfl_xor(ss, 1, 64);
    ss += __shfl_xor(ss, 2, 64);
    ss += __shfl_xor(ss, 4, 64);
    ss += __shfl_xor(ss, 8, 64);
    if (sub == 0) {
      const float nr = sqrtf(ss);
      norms[tok] = nr;
      inv_zn[t0b + tok] = 1.0f / fmaxf(nr, 1e-12f);
    }
  }
  __syncthreads();

  const int tk = lane & 15;
  const int kg = lane >> 4;

  f32x4 acc[2][8];
#pragma unroll
  for (int t = 0; t < 2; ++t)
#pragma unroll
    for (int c = 0; c < 8; ++c) acc[t][c] = (f32x4){0.f, 0.f, 0.f, 0.f};

  // wave's fragment stream base: ctiles wv*8..wv*8+7, 8KB per ctile
  const char* cfb = cbbf + (size_t)wv * 65536 + (size_t)lane * 16;

  // ---- K loop: 8 k-slices, fully unrolled, NO barriers
#pragma unroll
  for (int s = 0; s < 8; ++s) {
    bf16x8 zf[2];
#pragma unroll
    for (int tt = 0; tt < 2; ++tt) {
      const int tok = tt * 16 + tk;
      const int ku = (s << 2) + kg;
      zf[tt] = *(const bf16x8*)(S + (((tok << 5) + (ku ^ (tok & 15))) << 4));
    }
    bf16x8 cf[8];
#pragma unroll
    for (int ct = 0; ct < 8; ++ct)
      cf[ct] = *(const bf16x8*)(cfb + ct * 8192 + s * 1024);
#pragma unroll
    for (int ct = 0; ct < 8; ++ct) {
      acc[0][ct] = __builtin_amdgcn_mfma_f32_16x16x32_bf16(cf[ct], zf[0], acc[0][ct], 0, 0, 0);
      acc[1][ct] = __builtin_amdgcn_mfma_f32_16x16x32_bf16(cf[ct], zf[1], acc[1][ct], 0, 0, 0);
    }
  }

  // ---- per-wave top-2 (index for top-1) per token -> cand area
  // acc[tt][ct]: code = (wv<<7) + (ct<<4) + (kg<<2) + r   (VALIDATED r10)
#pragma unroll
  for (int tt = 0; tt < 2; ++tt) {
    float t1 = -3.0e38f, t2 = -3.0e38f;
    int i1 = 0;
#pragma unroll
    for (int ct = 0; ct < 8; ++ct)
#pragma unroll
      for (int r = 0; r < 4; ++r) {
        const float v = acc[tt][ct][r];
        const int k = (wv << 7) + (ct << 4) + (kg << 2) + r;
        if (v > t1) { t2 = t1; t1 = v; i1 = k; }
        else if (v > t2) t2 = v;
      }
#pragma unroll
    for (int off = 16; off <= 32; off <<= 1) {
      const float o1 = __shfl_xor(t1, off, 64);
      const int oi1 = __shfl_xor(i1, off, 64);
      const float o2 = __shfl_xor(t2, off, 64);
      const bool take = (o1 > t1) || (o1 == t1 && oi1 < i1);
      const float lo = take ? t1 : o1;
      t1 = take ? o1 : t1;
      i1 = take ? oi1 : i1;
      t2 = fmaxf(fmaxf(t2, o2), lo);
    }
    if (lane < 16) {
      int* p = cand + ((tt * 16 + lane) * 8 + wv) * 3;
      p[0] = __float_as_int(t1);
      p[1] = i1;
      p[2] = __float_as_int(t2);
    }
  }
  __syncthreads();

  // ---- resolver pass 1: thr + certified decision
  if (tid < 32) {
    const float nrm = norms[tid];
    const float margin = 0.016f * nrm + 1.5e-3f;  // 2*(2^-8+2^-8)*||z|| + slack
    const int* base = cand + tid * 24;
    float v1 = -3.0e38f, v2 = -3.0e38f;
    int j1 = 0x7fffffff;
#pragma unroll
    for (int w = 0; w < 8; ++w) {
      const float a1 = __int_as_float(base[w * 3]);
      const int ai = base[w * 3 + 1];
      const float a2 = __int_as_float(base[w * 3 + 2]);
      const bool take = (a1 > v1) || (a1 == v1 && ai < j1);
      const float lo = take ? v1 : a1;
      v1 = take ? a1 : v1;
      j1 = take ? ai : j1;
      v2 = fmaxf(fmaxf(v2, a2), lo);
    }
    const float thr = v1 - margin;
    thrs[tid] = (v2 < thr) ? 3.0e38f : thr;
    ccnt[tid] = 0;
    out_codes[t0b + tid] = (float)j1;  // final if certified, else provisional
  }
  __syncthreads();

  // ---- collect pass: append every code with S_bf >= thr (flagged tokens)
#pragma unroll
  for (int tt = 0; tt < 2; ++tt) {
    const int tok = tt * 16 + tk;
    const float thr_t = thrs[tok];
#pragma unroll
    for (int ct = 0; ct < 8; ++ct)
#pragma unroll
      for (int r = 0; r < 4; ++r) {
        if (acc[tt][ct][r] >= thr_t) {
          const int pos = atomicAdd(&ccnt[tok], 1);
          if (pos < 12)
            clist[tok * 12 + pos] = (wv << 7) + (ct << 4) + (kg << 2) + r;
        }
      }
  }
  __syncthreads();

  // ---- resolver pass 2: dense record (no caps, no fallback)
  if (tid < 32) {
    const int cnt = ccnt[tid];
    unsigned long long w0 = 0, w1 = 0;
    if (cnt > 0) {
      const int cc = cnt > 15 ? 15 : cnt;        // >12 -> full-scan flag
      w0 = (unsigned long long)cc << 60;
      const int nst = cnt > 12 ? 12 : cnt;
      for (int j = 0; j < nst && j < 6; ++j)
        w0 |= ((unsigned long long)(clist[tid * 12 + j] & 1023)) << (10 * j);
      for (int j = 6; j < nst; ++j)
        w1 |= ((unsigned long long)(clist[tid * 12 + j] & 1023)) << (10 * (j - 6));
    }
    cand2[2 * (t0b + tid)] = w0;
    cand2[2 * (t0b + tid) + 1] = w1;
  }
}

// ---------------------------------------------------------------- kernel 3
// exact recheck (r8-VALIDATED math) for cnt<=12; cnt>12 -> capless ovf list
__global__ __launch_bounds__(256) void recheck_kernel(
    const float* __restrict__ z, const float* __restrict__ cb,
    const double* __restrict__ inv_nc64,
    const unsigned long long* __restrict__ cand2,
    float* __restrict__ out_codes, int* __restrict__ ovf_list,
    int* __restrict__ ovf_cnt) {
  const int lane = threadIdx.x & 63;
  const int wid = (blockIdx.x * blockDim.x + threadIdx.x) >> 6;
  const int nw = (gridDim.x * blockDim.x) >> 6;
  for (int t = wid; t < N_TOK; t += nw) {
    const unsigned long long w0 = cand2[2 * t];
    if (w0 == 0ull) continue;
    const int cnt = (int)(w0 >> 60);
    if (cnt > 12) {  // defer to block-parallel full scan (capless list)
      if (lane == 0) ovf_list[atomicAdd(ovf_cnt, 1)] = t;
      continue;
    }
    const float4 zr = *(const float4*)(z + (size_t)t * D + lane * 4);
    const double z0 = zr.x, z1 = zr.y, z2 = zr.z, z3 = zr.w;
    const unsigned long long w1 = cand2[2 * t + 1];
    double best = -1.0e300;
    int bi = 0x7fffffff;
    for (int j = 0; j < cnt; ++j) {
      const int c = (j < 6) ? (int)((w0 >> (10 * j)) & 1023)
                            : (int)((w1 >> (10 * (j - 6))) & 1023);
      const float4 cr = *(const float4*)(cb + (size_t)c * D + lane * 4);
      double p = z0 * (double)cr.x + z1 * (double)cr.y +
                 z2 * (double)cr.z + z3 * (double)cr.w;
#pragma unroll
      for (int o = 32; o; o >>= 1) p += __shfl_xor(p, o, 64);
      p *= inv_nc64[c];
      if (p > best || (p == best && c < bi)) { best = p; bi = c; }
    }
    if (lane == 0) out_codes[t] = (float)bi;
  }
}

// ---------------------------------------------------------------- kernel 4
// block-parallel full scan: one 256-thread block per ovf token, fp64
__global__ __launch_bounds__(256) void fullscan_kernel(
    const float* __restrict__ z, const float* __restrict__ cb,
    const double* __restrict__ inv_nc64, const int* __restrict__ ovf_list,
    const int* __restrict__ ovf_cnt, float* __restrict__ out_codes) {
  __shared__ float zs[256];
  __shared__ double bv[256];
  __shared__ int bis[256];
  const int n = *ovf_cnt;
  for (int i = blockIdx.x; i < n; i += gridDim.x) {
    const int t = ovf_list[i];
    zs[threadIdx.x] = z[(size_t)t * D + threadIdx.x];
    __syncthreads();
    double best = -1.0e300;
    int bidx = 0x7fffffff;
#pragma unroll
    for (int cc = 0; cc < 4; ++cc) {
      const int c = threadIdx.x + (cc << 8);
      const float4* crow = (const float4*)(cb + (size_t)c * D);
      double p = 0.0;
#pragma unroll 8
      for (int k4 = 0; k4 < 64; ++k4) {
        const float4 cv = crow[k4];
        p += (double)zs[4 * k4] * (double)cv.x +
             (double)zs[4 * k4 + 1] * (double)cv.y +
             (double)zs[4 * k4 + 2] * (double)cv.z +
             (double)zs[4 * k4 + 3] * (double)cv.w;
      }
      p *= inv_nc64[c];
      if (p > best || (p == best && c < bidx)) { best = p; bidx = c; }
    }
    bv[threadIdx.x] = best;
    bis[threadIdx.x] = bidx;
    __syncthreads();
    for (int s = 128; s; s >>= 1) {
      if (threadIdx.x < s) {
        const double ov = bv[threadIdx.x + s];
        const int oi = bis[threadIdx.x + s];
        if (ov > bv[threadIdx.x] ||
            (ov == bv[threadIdx.x] && oi < bis[threadIdx.x])) {
          bv[threadIdx.x] = ov;
          bis[threadIdx.x] = oi;
        }
      }
      __syncthreads();
    }
    if (threadIdx.x == 0) out_codes[t] = (float)bis[0];
    __syncthreads();
  }
}

// ---------------------------------------------------------------- kernel 5
// histogram of final codes
__global__ __launch_bounds__(256) void hist_kernel(
    const float* __restrict__ codesf, int* __restrict__ hist) {
  const int t = blockIdx.x * 256 + threadIdx.x;
  if (t < N_TOK) atomicAdd(&hist[(int)codesf[t]], 1);
}

// ---------------------------------------------------------------- kernel 6
// exclusive scan of hist[1024] -> offsets[1025]; cursor = offsets copy
__global__ __launch_bounds__(256) void scan_kernel(
    const int* __restrict__ hist, int* __restrict__ offsets,
    int* __restrict__ cursor) {
  __shared__ int part[256];
  const int tid = threadIdx.x;
  int v[4];
  int s = 0;
#pragma unroll
  for (int j = 0; j < 4; ++j) {
    v[j] = hist[tid * 4 + j];
    s += v[j];
  }
  part[tid] = s;
  __syncthreads();
  for (int off = 1; off < 256; off <<= 1) {
    int x = (tid >= off) ? part[tid - off] : 0;
    __syncthreads();
    part[tid] += x;
    __syncthreads();
  }
  int excl = part[tid] - s;
#pragma unroll
  for (int j = 0; j < 4; ++j) {
    offsets[tid * 4 + j] = excl;
    cursor[tid * 4 + j] = excl;
    excl += v[j];
  }
  if (tid == 255) offsets[1024] = excl;  // = N_TOK
}

// ---------------------------------------------------------------- kernel 7
// scatter token ids into per-code segments
__global__ __launch_bounds__(256) void scatter_kernel(
    const float* __restrict__ codesf, int* __restrict__ cursor,
    int* __restrict__ tlist) {
  const int t = blockIdx.x * 256 + threadIdx.x;
  if (t < N_TOK) {
    const int c = (int)codesf[t];
    const int pos = atomicAdd(&cursor[c], 1);
    tlist[pos] = t;
  }
}

// ---------------------------------------------------------------- kernel 8
// embed[c] = l2norm(0.97*ema_w[c] + 0.03 * sum z[t]*inv_zn[t])  (r13 form)
__global__ __launch_bounds__(256) void dw_build_kernel(
    const float* __restrict__ z, const int* __restrict__ tlist,
    const int* __restrict__ offsets, const float* __restrict__ inv_zn,
    const float* __restrict__ ema_w, float* __restrict__ embed) {
  const int c = blockIdx.x;
  const int d = threadIdx.x;
  const int i0 = offsets[c], i1 = offsets[c + 1];
  float sum = 0.f;
  for (int i = i0; i < i1; ++i) {
    const int t = tlist[i];
    sum += z[(size_t)t * D + d] * inv_zn[t];
  }
  const size_t idx = (size_t)c * D + d;
  const float w = 0.97f * ema_w[idx] + 0.03f * sum;
  float ss = w * w;
#pragma unroll
  for (int o = 32; o; o >>= 1) ss += __shfl_down(ss, o, 64);
  __shared__ float red[4];
  if ((d & 63) == 0) red[d >> 6] = ss;
  __syncthreads();
  const float tot = red[0] + red[1] + red[2] + red[3];
  embed[idx] = w / fmaxf(sqrtf(tot), 1e-12f);
}

// ---------------------------------------------------------------- kernel 9
__global__ __launch_bounds__(256) void gather_loss_kernel(
    const float* __restrict__ z, const float* __restrict__ embed,
    const float* __restrict__ codesf, float* __restrict__ out0,
    double* __restrict__ loss) {
  const size_t u0 = (size_t)blockIdx.x * 4096 + threadIdx.x;
  float part = 0.f;
#pragma unroll 4
  for (int i = 0; i < 16; ++i) {
    const size_t u = u0 + (size_t)i * 256;
    const size_t t = u >> 6;
    const int k4 = (int)(u & 63);
    const int code = (int)codesf[t];
    const float4 e = *(const float4*)(embed + (size_t)code * D + 4 * k4);
    const float4 ze = *(const float4*)(z + t * D + 4 * k4);
    *(float4*)(out0 + t * D + 4 * k4) = e;
    const float dx = ze.x - e.x, dy = ze.y - e.y;
    const float dz = ze.z - e.z, dw4 = ze.w - e.w;
    part += dx * dx + dy * dy + dz * dz + dw4 * dw4;
  }
#pragma unroll
  for (int o = 32; o; o >>= 1) part += __shfl_down(part, o, 64);
  __shared__ float red[4];
  if ((threadIdx.x & 63) == 0) red[threadIdx.x >> 6] = part;
  __syncthreads();
  if (threadIdx.x == 0)
    unsafeAtomicAdd(loss, (double)(red[0] + red[1] + red[2] + red[3]));
}

// ---------------------------------------------------------------- kernel 10
__global__ void finalize_kernel(const double* __restrict__ loss,
                                float* __restrict__ out2) {
  out2[0] = (float)(0.25 * loss[0] / 33554432.0);
}

// ---------------------------------------------------------------- launcher
extern "C" void kernel_launch(void* const* d_in, const int* in_sizes, int n_in,
                              void* d_out, int out_size, void* d_ws, size_t ws_size,
                              hipStream_t stream) {
  const float* z = (const float*)d_in[0];
  const float* cb = (const float*)d_in[1];
  const float* ema_w = (const float*)d_in[3];

  float* out0 = (float*)d_out;
  float* out1 = out0 + (size_t)N_TOK * D;
  float* out2 = out1 + N_TOK;

  // ws layout: aliases validated r16-r18; inv_zn in the tail (r18-proven,
  // rounds 2-7 wrote up to 4.2MB without fault so ws_size >= 4.2MB).
  char* ws = (char*)d_ws;
  unsigned short* cbbf = (unsigned short*)ws;                       // [0, 512K)
  float* embed = (float*)ws;                                        // [0, 1M) alias
  int* ovf_list = (int*)(ws + 524288);                              // [512K, 1M)
  unsigned long long* cand2 = (unsigned long long*)(ws + 1048576);  // [1M, 3M)
  int* tlist = (int*)(ws + 1048576);                                // [1M, 1.5M) alias
  int* hist = (int*)(ws + 2097152);                                 // 4K alias
  int* offsets = (int*)(ws + 2101248);                              // 4K+4 alias
  int* cursor = (int*)(ws + 2105856);                               // 4K alias
  double* inv_nc64 = (double*)(ws + 3145728);                       // 8K
  double* loss = (double*)(ws + 3153920);                           // 8 B
  int* ovf_cnt = (int*)(ws + 3153984);                              // 4 B
  float* inv_zn = (float*)(ws + 3158016);                           // 512K tail

  hipMemsetAsync(ws + 3153920, 0, 128, stream);  // loss + ovf_cnt

  norm_cb_kernel<<<K_CODES, 256, 0, stream>>>(cb, inv_nc64, cbbf);
  vq_mfma_kernel<<<N_TOK / 32, 512, 0, stream>>>(
      z, (const char*)cbbf, out1, inv_zn, cand2);
  recheck_kernel<<<4096, 256, 0, stream>>>(z, cb, inv_nc64, cand2, out1,
                                           ovf_list, ovf_cnt);
  fullscan_kernel<<<2048, 256, 0, stream>>>(z, cb, inv_nc64, ovf_list,
                                            ovf_cnt, out1);
  hipMemsetAsync(hist, 0, 4096, stream);  // hist aliases dead cand2 region
  hist_kernel<<<N_TOK / 256, 256, 0, stream>>>(out1, hist);
  scan_kernel<<<1, 256, 0, stream>>>(hist, offsets, cursor);
  scatter_kernel<<<N_TOK / 256, 256, 0, stream>>>(out1, cursor, tlist);
  dw_build_kernel<<<K_CODES, 256, 0, stream>>>(z, tlist, offsets, inv_zn,
                                               ema_w, embed);
  gather_loss_kernel<<<2048, 256, 0, stream>>>(z, embed, out1, out0, loss);
  finalize_kernel<<<1, 1, 0, stream>>>(loss, out2);
}

// Round 20
// 391.397 us; speedup vs baseline: 1.0979x; 1.0077x over previous
//
#include <hip/hip_runtime.h>
#include <math.h>

#define N_TOK 131072
#define D 256
#define K_CODES 1024

typedef short bf16x8 __attribute__((ext_vector_type(8)));
typedef float f32x4 __attribute__((ext_vector_type(4)));

__device__ __forceinline__ unsigned short f2bf(float f) {
  unsigned x = __float_as_uint(f);
  unsigned r = x + 0x7fffu + ((x >> 16) & 1u);
  return (unsigned short)(r >> 16);
}

// ---------------------------------------------------------------- kernel 1
// fp64 code norms -> inv_nc64 (exact anchor, VALIDATED r8).
// cbb written FRAGMENT-MAJOR (VALIDATED r17): (c,d) -> frag[((c>>4)*8+(d>>5))
//   *64 + ((d>>3)&3)*16 + (c&15)][d&7]
__global__ __launch_bounds__(256) void norm_cb_kernel(
    const float* __restrict__ cb, double* __restrict__ inv_nc64,
    unsigned short* __restrict__ cbbf) {
  const int c = blockIdx.x;
  const int d = threadIdx.x;
  const float v = cb[(size_t)c * D + d];
  double ssd = (double)v * (double)v;
#pragma unroll
  for (int o = 32; o; o >>= 1) ssd += __shfl_down(ssd, o, 64);
  __shared__ double red[4];
  if ((d & 63) == 0) red[d >> 6] = ssd;
  __syncthreads();
  const double tot = red[0] + red[1] + red[2] + red[3];
  const double inv = 1.0 / fmax(sqrt(tot), 1e-12);
  if (d == 0) inv_nc64[c] = inv;
  const int ctile = c >> 4, tk = c & 15;
  const int s = d >> 5, kg = (d >> 3) & 3, e = d & 7;
  cbbf[(((size_t)(ctile * 8 + s) * 64) + (kg * 16 + tk)) * 8 + e] =
      f2bf((float)((double)v * inv));
}

// ---------------------------------------------------------------- kernel 2
// bf16 MFMA sims — r17-VALIDATED geometry (32 tok/block, barrier-free,
// fragment-major cf stream, inv_zn fused). r20: explicit register
// double-buffer on the cf stream (same loads + same MFMA order -> acc
// bit-identical; just issued one slice ahead).
__global__ __launch_bounds__(512, 2) void vq_mfma_kernel(
    const float* __restrict__ z, const char* __restrict__ cbbf,
    float* __restrict__ out_codes, float* __restrict__ inv_zn,
    unsigned long long* __restrict__ cand2) {
  __shared__ __align__(16) char S[16384];  // z tile bf16, swizzled 16B units
  __shared__ float norms[32];
  __shared__ int cand[32 * 8 * 3];
  __shared__ int clist[32 * 12];
  __shared__ float thrs[32];
  __shared__ int ccnt[32];

  const int tid = threadIdx.x;
  const int wv = tid >> 6;
  const int lane = tid & 63;
  const int t0b = blockIdx.x * 32;

  // ---- prologue: stage z (fp32->bf16, swizzled) + norms + inv_zn
  {
    const int tok = tid >> 4, sub = tid & 15;
    const float* zrow = z + (size_t)(t0b + tok) * D;
    float ss = 0.f;
#pragma unroll
    for (int i = 0; i < 2; ++i) {
      const int ku = sub + 16 * i;
      const float4 a = *(const float4*)(zrow + ku * 8);
      const float4 b = *(const float4*)(zrow + ku * 8 + 4);
      ss += a.x * a.x + a.y * a.y + a.z * a.z + a.w * a.w;
      ss += b.x * b.x + b.y * b.y + b.z * b.z + b.w * b.w;
      union { unsigned short h[8]; int4 v; } u;
      u.h[0] = f2bf(a.x); u.h[1] = f2bf(a.y); u.h[2] = f2bf(a.z); u.h[3] = f2bf(a.w);
      u.h[4] = f2bf(b.x); u.h[5] = f2bf(b.y); u.h[6] = f2bf(b.z); u.h[7] = f2bf(b.w);
      const int phys = (tok << 5) + (ku ^ (tok & 15));
      *(int4*)(S + ((size_t)phys << 4)) = u.v;
    }
    ss += __shfl_xor(ss, 1, 64);
    ss += __shfl_xor(ss, 2, 64);
    ss += __shfl_xor(ss, 4, 64);
    ss += __shfl_xor(ss, 8, 64);
    if (sub == 0) {
      const float nr = sqrtf(ss);
      norms[tok] = nr;
      inv_zn[t0b + tok] = 1.0f / fmaxf(nr, 1e-12f);
    }
  }
  __syncthreads();

  const int tk = lane & 15;
  const int kg = lane >> 4;

  f32x4 acc[2][8];
#pragma unroll
  for (int t = 0; t < 2; ++t)
#pragma unroll
    for (int c = 0; c < 8; ++c) acc[t][c] = (f32x4){0.f, 0.f, 0.f, 0.f};

  // wave's fragment stream base: ctiles wv*8..wv*8+7, 8KB per ctile
  const char* cfb = cbbf + (size_t)wv * 65536 + (size_t)lane * 16;

  // ---- K loop: 8 k-slices, register double-buffered cf, NO barriers
  bf16x8 cfA[8], cfB[8];
#pragma unroll
  for (int ct = 0; ct < 8; ++ct)
    cfA[ct] = *(const bf16x8*)(cfb + ct * 8192);
#pragma unroll
  for (int s = 0; s < 8; ++s) {
    // issue next slice's loads first (hide L2 latency under MFMAs)
    if (s < 7) {
      if ((s & 1) == 0) {
#pragma unroll
        for (int ct = 0; ct < 8; ++ct)
          cfB[ct] = *(const bf16x8*)(cfb + ct * 8192 + (s + 1) * 1024);
      } else {
#pragma unroll
        for (int ct = 0; ct < 8; ++ct)
          cfA[ct] = *(const bf16x8*)(cfb + ct * 8192 + (s + 1) * 1024);
      }
    }
    bf16x8 zf[2];
#pragma unroll
    for (int tt = 0; tt < 2; ++tt) {
      const int tok = tt * 16 + tk;
      const int ku = (s << 2) + kg;
      zf[tt] = *(const bf16x8*)(S + (((tok << 5) + (ku ^ (tok & 15))) << 4));
    }
    if ((s & 1) == 0) {
#pragma unroll
      for (int ct = 0; ct < 8; ++ct) {
        acc[0][ct] = __builtin_amdgcn_mfma_f32_16x16x32_bf16(cfA[ct], zf[0], acc[0][ct], 0, 0, 0);
        acc[1][ct] = __builtin_amdgcn_mfma_f32_16x16x32_bf16(cfA[ct], zf[1], acc[1][ct], 0, 0, 0);
      }
    } else {
#pragma unroll
      for (int ct = 0; ct < 8; ++ct) {
        acc[0][ct] = __builtin_amdgcn_mfma_f32_16x16x32_bf16(cfB[ct], zf[0], acc[0][ct], 0, 0, 0);
        acc[1][ct] = __builtin_amdgcn_mfma_f32_16x16x32_bf16(cfB[ct], zf[1], acc[1][ct], 0, 0, 0);
      }
    }
  }

  // ---- per-wave top-2 (index for top-1) per token -> cand area
  // acc[tt][ct]: code = (wv<<7) + (ct<<4) + (kg<<2) + r   (VALIDATED r10)
#pragma unroll
  for (int tt = 0; tt < 2; ++tt) {
    float t1 = -3.0e38f, t2 = -3.0e38f;
    int i1 = 0;
#pragma unroll
    for (int ct = 0; ct < 8; ++ct)
#pragma unroll
      for (int r = 0; r < 4; ++r) {
        const float v = acc[tt][ct][r];
        const int k = (wv << 7) + (ct << 4) + (kg << 2) + r;
        if (v > t1) { t2 = t1; t1 = v; i1 = k; }
        else if (v > t2) t2 = v;
      }
#pragma unroll
    for (int off = 16; off <= 32; off <<= 1) {
      const float o1 = __shfl_xor(t1, off, 64);
      const int oi1 = __shfl_xor(i1, off, 64);
      const float o2 = __shfl_xor(t2, off, 64);
      const bool take = (o1 > t1) || (o1 == t1 && oi1 < i1);
      const float lo = take ? t1 : o1;
      t1 = take ? o1 : t1;
      i1 = take ? oi1 : i1;
      t2 = fmaxf(fmaxf(t2, o2), lo);
    }
    if (lane < 16) {
      int* p = cand + ((tt * 16 + lane) * 8 + wv) * 3;
      p[0] = __float_as_int(t1);
      p[1] = i1;
      p[2] = __float_as_int(t2);
    }
  }
  __syncthreads();

  // ---- resolver pass 1: thr + certified decision
  if (tid < 32) {
    const float nrm = norms[tid];
    const float margin = 0.016f * nrm + 1.5e-3f;  // 2*(2^-8+2^-8)*||z|| + slack
    const int* base = cand + tid * 24;
    float v1 = -3.0e38f, v2 = -3.0e38f;
    int j1 = 0x7fffffff;
#pragma unroll
    for (int w = 0; w < 8; ++w) {
      const float a1 = __int_as_float(base[w * 3]);
      const int ai = base[w * 3 + 1];
      const float a2 = __int_as_float(base[w * 3 + 2]);
      const bool take = (a1 > v1) || (a1 == v1 && ai < j1);
      const float lo = take ? v1 : a1;
      v1 = take ? a1 : v1;
      j1 = take ? ai : j1;
      v2 = fmaxf(fmaxf(v2, a2), lo);
    }
    const float thr = v1 - margin;
    thrs[tid] = (v2 < thr) ? 3.0e38f : thr;
    ccnt[tid] = 0;
    out_codes[t0b + tid] = (float)j1;  // final if certified, else provisional
  }
  __syncthreads();

  // ---- collect pass: append every code with S_bf >= thr (flagged tokens)
#pragma unroll
  for (int tt = 0; tt < 2; ++tt) {
    const int tok = tt * 16 + tk;
    const float thr_t = thrs[tok];
#pragma unroll
    for (int ct = 0; ct < 8; ++ct)
#pragma unroll
      for (int r = 0; r < 4; ++r) {
        if (acc[tt][ct][r] >= thr_t) {
          const int pos = atomicAdd(&ccnt[tok], 1);
          if (pos < 12)
            clist[tok * 12 + pos] = (wv << 7) + (ct << 4) + (kg << 2) + r;
        }
      }
  }
  __syncthreads();

  // ---- resolver pass 2: dense record (no caps, no fallback)
  if (tid < 32) {
    const int cnt = ccnt[tid];
    unsigned long long w0 = 0, w1 = 0;
    if (cnt > 0) {
      const int cc = cnt > 15 ? 15 : cnt;        // >12 -> full-scan flag
      w0 = (unsigned long long)cc << 60;
      const int nst = cnt > 12 ? 12 : cnt;
      for (int j = 0; j < nst && j < 6; ++j)
        w0 |= ((unsigned long long)(clist[tid * 12 + j] & 1023)) << (10 * j);
      for (int j = 6; j < nst; ++j)
        w1 |= ((unsigned long long)(clist[tid * 12 + j] & 1023)) << (10 * (j - 6));
    }
    cand2[2 * (t0b + tid)] = w0;
    cand2[2 * (t0b + tid) + 1] = w1;
  }
}

// ---------------------------------------------------------------- kernel 3
// exact recheck (r8-VALIDATED math) for cnt<=12; cnt>12 -> capless ovf list
__global__ __launch_bounds__(256) void recheck_kernel(
    const float* __restrict__ z, const float* __restrict__ cb,
    const double* __restrict__ inv_nc64,
    const unsigned long long* __restrict__ cand2,
    float* __restrict__ out_codes, int* __restrict__ ovf_list,
    int* __restrict__ ovf_cnt) {
  const int lane = threadIdx.x & 63;
  const int wid = (blockIdx.x * blockDim.x + threadIdx.x) >> 6;
  const int nw = (gridDim.x * blockDim.x) >> 6;
  for (int t = wid; t < N_TOK; t += nw) {
    const unsigned long long w0 = cand2[2 * t];
    if (w0 == 0ull) continue;
    const int cnt = (int)(w0 >> 60);
    if (cnt > 12) {  // defer to block-parallel full scan (capless list)
      if (lane == 0) ovf_list[atomicAdd(ovf_cnt, 1)] = t;
      continue;
    }
    const float4 zr = *(const float4*)(z + (size_t)t * D + lane * 4);
    const double z0 = zr.x, z1 = zr.y, z2 = zr.z, z3 = zr.w;
    const unsigned long long w1 = cand2[2 * t + 1];
    double best = -1.0e300;
    int bi = 0x7fffffff;
    for (int j = 0; j < cnt; ++j) {
      const int c = (j < 6) ? (int)((w0 >> (10 * j)) & 1023)
                            : (int)((w1 >> (10 * (j - 6))) & 1023);
      const float4 cr = *(const float4*)(cb + (size_t)c * D + lane * 4);
      double p = z0 * (double)cr.x + z1 * (double)cr.y +
                 z2 * (double)cr.z + z3 * (double)cr.w;
#pragma unroll
      for (int o = 32; o; o >>= 1) p += __shfl_xor(p, o, 64);
      p *= inv_nc64[c];
      if (p > best || (p == best && c < bi)) { best = p; bi = c; }
    }
    if (lane == 0) out_codes[t] = (float)bi;
  }
}

// ---------------------------------------------------------------- kernel 4
// block-parallel full scan: one 256-thread block per ovf token, fp64
__global__ __launch_bounds__(256) void fullscan_kernel(
    const float* __restrict__ z, const float* __restrict__ cb,
    const double* __restrict__ inv_nc64, const int* __restrict__ ovf_list,
    const int* __restrict__ ovf_cnt, float* __restrict__ out_codes) {
  __shared__ float zs[256];
  __shared__ double bv[256];
  __shared__ int bis[256];
  const int n = *ovf_cnt;
  for (int i = blockIdx.x; i < n; i += gridDim.x) {
    const int t = ovf_list[i];
    zs[threadIdx.x] = z[(size_t)t * D + threadIdx.x];
    __syncthreads();
    double best = -1.0e300;
    int bidx = 0x7fffffff;
#pragma unroll
    for (int cc = 0; cc < 4; ++cc) {
      const int c = threadIdx.x + (cc << 8);
      const float4* crow = (const float4*)(cb + (size_t)c * D);
      double p = 0.0;
#pragma unroll 8
      for (int k4 = 0; k4 < 64; ++k4) {
        const float4 cv = crow[k4];
        p += (double)zs[4 * k4] * (double)cv.x +
             (double)zs[4 * k4 + 1] * (double)cv.y +
             (double)zs[4 * k4 + 2] * (double)cv.z +
             (double)zs[4 * k4 + 3] * (double)cv.w;
      }
      p *= inv_nc64[c];
      if (p > best || (p == best && c < bidx)) { best = p; bidx = c; }
    }
    bv[threadIdx.x] = best;
    bis[threadIdx.x] = bidx;
    __syncthreads();
    for (int s = 128; s; s >>= 1) {
      if (threadIdx.x < s) {
        const double ov = bv[threadIdx.x + s];
        const int oi = bis[threadIdx.x + s];
        if (ov > bv[threadIdx.x] ||
            (ov == bv[threadIdx.x] && oi < bis[threadIdx.x])) {
          bv[threadIdx.x] = ov;
          bis[threadIdx.x] = oi;
        }
      }
      __syncthreads();
    }
    if (threadIdx.x == 0) out_codes[t] = (float)bis[0];
    __syncthreads();
  }
}

// ---------------------------------------------------------------- kernel 5
// histogram of final codes
__global__ __launch_bounds__(256) void hist_kernel(
    const float* __restrict__ codesf, int* __restrict__ hist) {
  const int t = blockIdx.x * 256 + threadIdx.x;
  if (t < N_TOK) atomicAdd(&hist[(int)codesf[t]], 1);
}

// ---------------------------------------------------------------- kernel 6
// exclusive scan of hist[1024] -> offsets[1025]; cursor = offsets copy
__global__ __launch_bounds__(256) void scan_kernel(
    const int* __restrict__ hist, int* __restrict__ offsets,
    int* __restrict__ cursor) {
  __shared__ int part[256];
  const int tid = threadIdx.x;
  int v[4];
  int s = 0;
#pragma unroll
  for (int j = 0; j < 4; ++j) {
    v[j] = hist[tid * 4 + j];
    s += v[j];
  }
  part[tid] = s;
  __syncthreads();
  for (int off = 1; off < 256; off <<= 1) {
    int x = (tid >= off) ? part[tid - off] : 0;
    __syncthreads();
    part[tid] += x;
    __syncthreads();
  }
  int excl = part[tid] - s;
#pragma unroll
  for (int j = 0; j < 4; ++j) {
    offsets[tid * 4 + j] = excl;
    cursor[tid * 4 + j] = excl;
    excl += v[j];
  }
  if (tid == 255) offsets[1024] = excl;  // = N_TOK
}

// ---------------------------------------------------------------- kernel 7
// scatter token ids into per-code segments
__global__ __launch_bounds__(256) void scatter_kernel(
    const float* __restrict__ codesf, int* __restrict__ cursor,
    int* __restrict__ tlist) {
  const int t = blockIdx.x * 256 + threadIdx.x;
  if (t < N_TOK) {
    const int c = (int)codesf[t];
    const int pos = atomicAdd(&cursor[c], 1);
    tlist[pos] = t;
  }
}

// ---------------------------------------------------------------- kernel 8
// embed[c] = l2norm(0.97*ema_w[c] + 0.03 * sum z[t]*inv_zn[t])  (r13 form)
__global__ __launch_bounds__(256) void dw_build_kernel(
    const float* __restrict__ z, const int* __restrict__ tlist,
    const int* __restrict__ offsets, const float* __restrict__ inv_zn,
    const float* __restrict__ ema_w, float* __restrict__ embed) {
  const int c = blockIdx.x;
  const int d = threadIdx.x;
  const int i0 = offsets[c], i1 = offsets[c + 1];
  float sum = 0.f;
  for (int i = i0; i < i1; ++i) {
    const int t = tlist[i];
    sum += z[(size_t)t * D + d] * inv_zn[t];
  }
  const size_t idx = (size_t)c * D + d;
  const float w = 0.97f * ema_w[idx] + 0.03f * sum;
  float ss = w * w;
#pragma unroll
  for (int o = 32; o; o >>= 1) ss += __shfl_down(ss, o, 64);
  __shared__ float red[4];
  if ((d & 63) == 0) red[d >> 6] = ss;
  __syncthreads();
  const float tot = red[0] + red[1] + red[2] + red[3];
  embed[idx] = w / fmaxf(sqrtf(tot), 1e-12f);
}

// ---------------------------------------------------------------- kernel 9
__global__ __launch_bounds__(256) void gather_loss_kernel(
    const float* __restrict__ z, const float* __restrict__ embed,
    const float* __restrict__ codesf, float* __restrict__ out0,
    double* __restrict__ loss) {
  const size_t u0 = (size_t)blockIdx.x * 4096 + threadIdx.x;
  float part = 0.f;
#pragma unroll 4
  for (int i = 0; i < 16; ++i) {
    const size_t u = u0 + (size_t)i * 256;
    const size_t t = u >> 6;
    const int k4 = (int)(u & 63);
    const int code = (int)codesf[t];
    const float4 e = *(const float4*)(embed + (size_t)code * D + 4 * k4);
    const float4 ze = *(const float4*)(z + t * D + 4 * k4);
    *(float4*)(out0 + t * D + 4 * k4) = e;
    const float dx = ze.x - e.x, dy = ze.y - e.y;
    const float dz = ze.z - e.z, dw4 = ze.w - e.w;
    part += dx * dx + dy * dy + dz * dz + dw4 * dw4;
  }
#pragma unroll
  for (int o = 32; o; o >>= 1) part += __shfl_down(part, o, 64);
  __shared__ float red[4];
  if ((threadIdx.x & 63) == 0) red[threadIdx.x >> 6] = part;
  __syncthreads();
  if (threadIdx.x == 0)
    unsafeAtomicAdd(loss, (double)(red[0] + red[1] + red[2] + red[3]));
}

// ---------------------------------------------------------------- kernel 10
__global__ void finalize_kernel(const double* __restrict__ loss,
                                float* __restrict__ out2) {
  out2[0] = (float)(0.25 * loss[0] / 33554432.0);
}

// ---------------------------------------------------------------- launcher
extern "C" void kernel_launch(void* const* d_in, const int* in_sizes, int n_in,
                              void* d_out, int out_size, void* d_ws, size_t ws_size,
                              hipStream_t stream) {
  const float* z = (const float*)d_in[0];
  const float* cb = (const float*)d_in[1];
  const float* ema_w = (const float*)d_in[3];

  float* out0 = (float*)d_out;
  float* out1 = out0 + (size_t)N_TOK * D;
  float* out2 = out1 + N_TOK;

  // ws layout: aliases validated r16-r19 (max offset 3,682,304, r19-proven)
  char* ws = (char*)d_ws;
  unsigned short* cbbf = (unsigned short*)ws;                       // [0, 512K)
  float* embed = (float*)ws;                                        // [0, 1M) alias
  int* ovf_list = (int*)(ws + 524288);                              // [512K, 1M)
  unsigned long long* cand2 = (unsigned long long*)(ws + 1048576);  // [1M, 3M)
  int* tlist = (int*)(ws + 1048576);                                // [1M, 1.5M) alias
  int* hist = (int*)(ws + 2097152);                                 // 4K alias
  int* offsets = (int*)(ws + 2101248);                              // 4K+4 alias
  int* cursor = (int*)(ws + 2105856);                               // 4K alias
  double* inv_nc64 = (double*)(ws + 3145728);                       // 8K
  double* loss = (double*)(ws + 3153920);                           // 8 B
  int* ovf_cnt = (int*)(ws + 3153984);                              // 4 B
  float* inv_zn = (float*)(ws + 3158016);                           // 512K tail

  hipMemsetAsync(ws + 3153920, 0, 128, stream);  // loss + ovf_cnt

  norm_cb_kernel<<<K_CODES, 256, 0, stream>>>(cb, inv_nc64, cbbf);
  vq_mfma_kernel<<<N_TOK / 32, 512, 0, stream>>>(
      z, (const char*)cbbf, out1, inv_zn, cand2);
  recheck_kernel<<<4096, 256, 0, stream>>>(z, cb, inv_nc64, cand2, out1,
                                           ovf_list, ovf_cnt);
  fullscan_kernel<<<2048, 256, 0, stream>>>(z, cb, inv_nc64, ovf_list,
                                            ovf_cnt, out1);
  hipMemsetAsync(hist, 0, 4096, stream);  // hist aliases dead cand2 region
  hist_kernel<<<N_TOK / 256, 256, 0, stream>>>(out1, hist);
  scan_kernel<<<1, 256, 0, stream>>>(hist, offsets, cursor);
  scatter_kernel<<<N_TOK / 256, 256, 0, stream>>>(out1, cursor, tlist);
  dw_build_kernel<<<K_CODES, 256, 0, stream>>>(z, tlist, offsets, inv_zn,
                                               ema_w, embed);
  gather_loss_kernel<<<2048, 256, 0, stream>>>(z, embed, out1, out0, loss);
  finalize_kernel<<<1, 1, 0, stream>>>(loss, out2);
}